// Round 5
// baseline (895.834 us; speedup 1.0000x reference)
//
#include <hip/hip_runtime.h>
#include <cmath>

#define D_MODEL 1024
#define D_STATE 16
#define D_INNER 2048
#define NB 4
#define SEQL 2048
#define ROWS (NB*SEQL)        // 8192
#define XZ_LD (2*D_INNER)     // 4096

typedef __attribute__((ext_vector_type(8))) short short8;
typedef __attribute__((ext_vector_type(4))) float f32x4;

__device__ __forceinline__ float sigmoidf_(float v) { return 1.0f / (1.0f + __expf(-v)); }

__device__ __forceinline__ unsigned short bf16rne(float f) {
    unsigned u = __float_as_uint(f);
    unsigned r = (u + 0x7FFFu + ((u >> 16) & 1u)) >> 16;
    return (unsigned short)r;
}

// ---------------- fp32 -> packed split-bf16 layouts ----------------
// pack2: R x K fp32 -> R x 2K bf16 rows [hi | lo]          (A-side)
__global__ __launch_bounds__(256) void pack2_k(const float4* __restrict__ in,
    ushort4* __restrict__ out, int l2K4, int n4)
{
    int i = blockIdx.x * 256 + threadIdx.x;
    if (i >= n4) return;
    int K4 = 1 << l2K4;
    int r = i >> l2K4, c = i & (K4 - 1);
    float4 v = in[i];
    ushort4 h, l;
    h.x = bf16rne(v.x); l.x = bf16rne(v.x - __uint_as_float((unsigned)h.x << 16));
    h.y = bf16rne(v.y); l.y = bf16rne(v.y - __uint_as_float((unsigned)h.y << 16));
    h.z = bf16rne(v.z); l.z = bf16rne(v.z - __uint_as_float((unsigned)h.z << 16));
    h.w = bf16rne(v.w); l.w = bf16rne(v.w - __uint_as_float((unsigned)h.w << 16));
    size_t base = (size_t)r * 2 * K4 + c;
    out[base] = h;
    out[base + K4] = l;
}

// pack3: R x K fp32 -> R x 3K bf16 rows [hi | hi | lo]     (B-side)
__global__ __launch_bounds__(256) void pack3_k(const float4* __restrict__ in,
    ushort4* __restrict__ out, int l2K4, int n4)
{
    int i = blockIdx.x * 256 + threadIdx.x;
    if (i >= n4) return;
    int K4 = 1 << l2K4;
    int r = i >> l2K4, c = i & (K4 - 1);
    float4 v = in[i];
    ushort4 h, l;
    h.x = bf16rne(v.x); l.x = bf16rne(v.x - __uint_as_float((unsigned)h.x << 16));
    h.y = bf16rne(v.y); l.y = bf16rne(v.y - __uint_as_float((unsigned)h.y << 16));
    h.z = bf16rne(v.z); l.z = bf16rne(v.z - __uint_as_float((unsigned)h.z << 16));
    h.w = bf16rne(v.w); l.w = bf16rne(v.w - __uint_as_float((unsigned)h.w << 16));
    size_t base = (size_t)r * 3 * K4 + c;
    out[base] = h;
    out[base + K4] = h;
    out[base + 2 * K4] = l;
}

// ---------------- big-tile bf16 NT GEMM, 3-buffer counted-vmcnt pipeline ----------------
// C(M,N) += A2(M,KA) x B2(N,KB)^T over k' = 0..KB, where A column = k' (wrapped mod KA).
// BM x 256 tile, 8 waves (2Mx4N), BK'=32, 16x16x32 bf16 MFMA.
// LDS: 3 buffers, k-slot-major [4 slots][rows][8 elems] per operand (conflict-free for
// linear global_load_lds AND b128 fragment reads). Schedule per K-step:
//   vmcnt(L) [own tile-t loads done; tile-t+1 stays in flight] -> s_barrier ->
//   stage tile t+2 -> ds_read frags -> setprio(1) -> MFMA cluster -> setprio(0).
#define GLDS(gp, lp) __builtin_amdgcn_global_load_lds( \
    (const __attribute__((address_space(1))) void*)(gp), \
    (__attribute__((address_space(3))) void*)(lp), 16, 0, 0)

template<int BM>
__global__ __launch_bounds__(512, 2) void gemm3k(
    const unsigned short* __restrict__ A2, int KA,
    const unsigned short* __restrict__ B2, int KB,
    float* __restrict__ C, int ldc)
{
    constexpr int ASW = BM / 128;          // A staging sweeps per K-step
    constexpr int WM  = BM / 2;            // per-wave M rows
    constexpr int MF  = WM / 16;           // A fragments per wave
    constexpr int ABUF = 4 * BM * 8;       // ushorts per A buffer
    constexpr int BBUF = 4 * 256 * 8;      // ushorts per B buffer
    extern __shared__ __align__(16) unsigned short smem[];
    unsigned short* sAb = smem;                    // 3 * ABUF
    unsigned short* sBb = smem + 3 * ABUF;         // 3 * BBUF

    const int tid = threadIdx.x;
    const int bm = blockIdx.y * BM, bn = blockIdx.x * 256;
    const int wave = tid >> 6, lane = tid & 63;
    const int wm = wave >> 2, wn = wave & 3;
    const int fr = lane & 15, kq = lane >> 4;
    const int NT = KB / 32;

    auto stage = [&](int bi, int t) {
        int k0 = t * 32;
        int kb = (k0 < KA) ? k0 : k0 - KA;       // A-side wrap (slice 2 re-reads hi)
        unsigned short* aB = sAb + bi * ABUF;
        unsigned short* bB = sBb + bi * BBUF;
#pragma unroll
        for (int s2 = 0; s2 < ASW; ++s2) {
            int c = s2 * 512 + tid;
            int row = c & (BM - 1), slot = (BM == 256) ? (c >> 8) : (c >> 7);
            GLDS(A2 + (size_t)(bm + row) * KA + kb + slot * 8, aB + c * 8);
        }
#pragma unroll
        for (int s2 = 0; s2 < 2; ++s2) {
            int c = s2 * 512 + tid;
            int row = c & 255, slot = c >> 8;
            GLDS(B2 + (size_t)(bn + row) * KB + k0 + slot * 8, bB + c * 8);
        }
    };

    f32x4 acc[MF][4];
#pragma unroll
    for (int m = 0; m < MF; ++m)
#pragma unroll
        for (int n = 0; n < 4; ++n) acc[m][n] = (f32x4){0.f, 0.f, 0.f, 0.f};

    stage(0, 0);
    stage(1, 1);

    int cur = 0;
    for (int t = 0; t < NT; ++t) {
        if (t + 2 < NT) {
            if constexpr (ASW + 2 == 4) asm volatile("s_waitcnt vmcnt(4)" ::: "memory");
            else                        asm volatile("s_waitcnt vmcnt(3)" ::: "memory");
        } else {
            asm volatile("s_waitcnt vmcnt(0)" ::: "memory");
        }
        __builtin_amdgcn_s_barrier();
        asm volatile("" ::: "memory");
        if (t + 2 < NT) {
            int nb = cur + 2; if (nb >= 3) nb -= 3;
            stage(nb, t + 2);
        }
        const unsigned short* cA = sAb + cur * ABUF;
        const unsigned short* cB = sBb + cur * BBUF;
        short8 a[MF], b[4];
#pragma unroll
        for (int m = 0; m < MF; ++m)
            a[m] = *(const short8*)&cA[(kq * BM + wm * WM + m * 16 + fr) * 8];
#pragma unroll
        for (int n = 0; n < 4; ++n)
            b[n] = *(const short8*)&cB[(kq * 256 + wn * 64 + n * 16 + fr) * 8];
        __builtin_amdgcn_s_setprio(1);
#pragma unroll
        for (int m = 0; m < MF; ++m)
#pragma unroll
            for (int n = 0; n < 4; ++n)
                acc[m][n] = __builtin_amdgcn_mfma_f32_16x16x32_bf16(a[m], b[n], acc[m][n], 0, 0, 0);
        __builtin_amdgcn_s_setprio(0);
        ++cur; if (cur >= 3) cur = 0;
    }

    // C/D layout: col = lane&15, row = (lane>>4)*4 + j
#pragma unroll
    for (int m = 0; m < MF; ++m) {
        int row0 = bm + wm * WM + m * 16 + kq * 4;
#pragma unroll
        for (int j = 0; j < 4; ++j) {
            float* Cr = C + (size_t)(row0 + j) * ldc + bn + wn * 64 + fr;
#pragma unroll
            for (int n = 0; n < 4; ++n) Cr[n * 16] = acc[m][n][j];
        }
    }
}

// ---------------- causal depthwise conv (D_CONV=4) + SiLU ----------------
__global__ __launch_bounds__(256) void conv_silu_k(
    const float* __restrict__ xz, const float* __restrict__ conv_w,
    const float* __restrict__ conv_b, float* __restrict__ x_conv)
{
    int idx = blockIdx.x * 256 + threadIdx.x;   // ROWS * 512 total
    int q = idx & 511;
    int r = idx >> 9;
    int b = r >> 11, t = r & (SEQL - 1);
    int d0 = q << 2;
    float w[4][4];
#pragma unroll
    for (int c = 0; c < 4; ++c) *(float4*)w[c] = *(const float4*)&conv_w[(d0 + c) * 4];
    float4 acc = *(const float4*)&conv_b[d0];
    const float* xp = xz + (size_t)(b * SEQL) * XZ_LD + d0;
#pragma unroll
    for (int k = 0; k < 4; ++k) {
        int t2 = t - 3 + k;
        if (t2 >= 0) {
            float4 v = *(const float4*)(xp + (size_t)t2 * XZ_LD);
            acc.x = fmaf(v.x, w[0][k], acc.x);
            acc.y = fmaf(v.y, w[1][k], acc.y);
            acc.z = fmaf(v.z, w[2][k], acc.z);
            acc.w = fmaf(v.w, w[3][k], acc.w);
        }
    }
    acc.x *= sigmoidf_(acc.x);
    acc.y *= sigmoidf_(acc.y);
    acc.z *= sigmoidf_(acc.z);
    acc.w *= sigmoidf_(acc.w);
    *(float4*)&x_conv[(size_t)r * D_INNER + d0] = acc;
}

// ---------------- x_proj: 33 dots of length 2048 per row -> A_bar/B_bar/C ----------------
__global__ __launch_bounds__(256) void proj_k(
    const float* __restrict__ x_conv, const float* __restrict__ W_xproj,
    const float* __restrict__ A_log,
    float* __restrict__ Abar, float* __restrict__ Bbar, float* __restrict__ Cmat)
{
    __shared__ float sdbl[4][33];
    int tid = threadIdx.x;
    int w = tid >> 6, lane = tid & 63;
    int row = blockIdx.x * 4 + w;
    const float* xrow = x_conv + (size_t)row * D_INNER;
    float4 xr[8];
#pragma unroll
    for (int it = 0; it < 8; ++it)
        xr[it] = *(const float4*)&xrow[it * 256 + lane * 4];

    for (int j = 0; j < 33; ++j) {
        const float* wrow = W_xproj + j * D_INNER;
        float accv = 0.f;
#pragma unroll
        for (int it = 0; it < 8; ++it) {
            float4 wv = *(const float4*)&wrow[it * 256 + lane * 4];
            accv = fmaf(xr[it].x, wv.x, accv);
            accv = fmaf(xr[it].y, wv.y, accv);
            accv = fmaf(xr[it].z, wv.z, accv);
            accv = fmaf(xr[it].w, wv.w, accv);
        }
#pragma unroll
        for (int off = 32; off; off >>= 1) accv += __shfl_xor(accv, off);
        if (lane == 0) sdbl[w][j] = accv;
    }
    __syncthreads();
    if (tid < 64) {
        int w2 = tid >> 4, s = tid & 15;
        int row2 = blockIdx.x * 4 + w2;
        float draw = sdbl[w2][32];
        float sp = (draw > 20.f) ? draw : log1pf(__expf(draw));
        float dt = fminf(fmaxf(sp, 0.001f), 0.1f);
        float Aa = -__expf(A_log[s]);
        float dtA = fminf(fmaxf(dt * Aa, -20.f), 0.f);
        Abar[row2 * 16 + s] = __expf(dtA);
        float bb = dt * sdbl[w2][s];
        Bbar[row2 * 16 + s] = fminf(fmaxf(bb, -10.f), 10.f);
        Cmat[row2 * 16 + s] = sdbl[w2][16 + s];
    }
}

// ---------------- SSM scan: 1 state per lane, 16 lanes per channel ----------------
#define SCH 16
#define TT 16
__global__ __launch_bounds__(256) void scan_k(
    float* __restrict__ x_conv, const float* __restrict__ xz,
    const float* __restrict__ Abar, const float* __restrict__ Bbar,
    const float* __restrict__ Cmat, const float* __restrict__ D_param)
{
    __shared__ __align__(16) float sXa[2][SCH][TT];        // [ch][t]
    __shared__ float sZp[2][SCH][TT + 1];
    __shared__ __align__(16) float sPa[2][16][20];         // [s][t], pad 20
    __shared__ __align__(16) float sPb[2][16][20];
    __shared__ __align__(16) float sPc[2][16][20];
    __shared__ __align__(16) float sT[SCH][328];           // [ch][t*20 + s]

    const int tid = threadIdx.x;
    const int b = blockIdx.y, dbase = blockIdx.x * SCH;
    const int chl = tid >> 4, s = tid & 15;
    float* xc = x_conv + (size_t)(b * SEQL) * D_INNER + dbase;
    const float* zp = xz + (size_t)(b * SEQL) * XZ_LD + D_INNER + dbase;
    const int pbase0 = (b * SEQL) * 16;
    const int st = tid >> 4, sc = tid & 15;

    auto stage = [&](int buf, int tc) {
        int t0 = tc * TT;
        sXa[buf][sc][st] = xc[(size_t)(t0 + st) * D_INNER + sc];
        sZp[buf][sc][st] = zp[(size_t)(t0 + st) * XZ_LD + sc];
        int g = pbase0 + t0 * 16 + tid;
        sPa[buf][sc][st] = Abar[g];
        sPb[buf][sc][st] = Bbar[g];
        sPc[buf][sc][st] = Cmat[g];
    };

    stage(0, 0);
    float h = 0.f;
    const float Dp = D_param[dbase + chl];

    for (int tc = 0; tc < SEQL / TT; ++tc) {
        int buf = tc & 1;
        __syncthreads();
        if (tc + 1 < SEQL / TT) stage(buf ^ 1, tc + 1);

        float p[16];
#pragma unroll
        for (int q = 0; q < 4; ++q) {
            float4 a4 = *(const float4*)&sPa[buf][s][q * 4];
            float4 b4 = *(const float4*)&sPb[buf][s][q * 4];
            float4 c4 = *(const float4*)&sPc[buf][s][q * 4];
            float4 x4 = *(const float4*)&sXa[buf][chl][q * 4];
            h = fminf(fmaxf(fmaf(b4.x, x4.x, a4.x * h), -100.f), 100.f); p[q * 4 + 0] = h * c4.x;
            h = fminf(fmaxf(fmaf(b4.y, x4.y, a4.y * h), -100.f), 100.f); p[q * 4 + 1] = h * c4.y;
            h = fminf(fmaxf(fmaf(b4.z, x4.z, a4.z * h), -100.f), 100.f); p[q * 4 + 2] = h * c4.z;
            h = fminf(fmaxf(fmaf(b4.w, x4.w, a4.w * h), -100.f), 100.f); p[q * 4 + 3] = h * c4.w;
        }
#pragma unroll
        for (int i = 0; i < 16; ++i) sT[chl][i * 20 + s] = p[i];
        float4 r0 = *(const float4*)&sT[chl][s * 20 + 0];
        float4 r1 = *(const float4*)&sT[chl][s * 20 + 4];
        float4 r2 = *(const float4*)&sT[chl][s * 20 + 8];
        float4 r3 = *(const float4*)&sT[chl][s * 20 + 12];
        float ysum = ((r0.x + r1.x + r2.x + r3.x) + (r0.y + r1.y + r2.y + r3.y))
                   + ((r0.z + r1.z + r2.z + r3.z) + (r0.w + r1.w + r2.w + r3.w));
        float z = sZp[buf][chl][s];
        float x = sXa[buf][chl][s];
        float o = fmaf(x, Dp, ysum * (z * sigmoidf_(z)));
        xc[(size_t)(tc * TT + s) * D_INNER + chl] = o;
    }
}

extern "C" void kernel_launch(void* const* d_in, const int* in_sizes, int n_in,
                              void* d_out, int out_size, void* d_ws, size_t ws_size,
                              hipStream_t stream) {
    const float* x       = (const float*)d_in[0];
    const float* W_in    = (const float*)d_in[1];
    const float* conv_w  = (const float*)d_in[2];
    const float* conv_b  = (const float*)d_in[3];
    const float* W_xproj = (const float*)d_in[4];
    const float* A_log   = (const float*)d_in[5];
    const float* D_param = (const float*)d_in[6];
    const float* W_out   = (const float*)d_in[7];
    float* out = (float*)d_out;

    // ---- workspace: round-1 footprint (202.9 MB), phase-aliased ----
    char* p = (char*)d_ws;
    char* xzB = p;
    float* xz = (float*)xzB;                 // 134.2 MB
    p += (size_t)ROWS * XZ_LD * 4;
    char* xcB = p;
    float* x_conv = (float*)xcB;             // 67.1 MB
    p += (size_t)ROWS * D_INNER * 4;
    float* Abar = (float*)p; p += (size_t)ROWS * 16 * 4;
    float* Bbar = (float*)p; p += (size_t)ROWS * 16 * 4;
    float* Cm   = (float*)p; p += (size_t)ROWS * 16 * 4;

    // phase-0 aliases in x_conv region: x2 (8192x2048 bf16) + W_in2 (4096x3072 bf16) = 58.7 MB
    unsigned short* x2  = (unsigned short*)xcB;
    unsigned short* Wi2 = x2 + (size_t)ROWS * 2 * D_MODEL;
    // phase-3 aliases in xz region: y2 (8192x4096 bf16) + W_out2 (1024x6144 bf16) = 79.7 MB
    unsigned short* y2  = (unsigned short*)xzB;
    unsigned short* Wo2 = y2 + (size_t)ROWS * 2 * D_INNER;

    constexpr int SM1 = (3 * 4 * 256 * 8 + 3 * 4 * 256 * 8) * 2;  // 96 KiB
    constexpr int SM2 = (3 * 4 * 128 * 8 + 3 * 4 * 256 * 8) * 2;  // 72 KiB

    // 0) pack x -> [hi|lo], W_in -> [hi|hi|lo]
    pack2_k<<<ROWS * D_MODEL / 4 / 256, 256, 0, stream>>>(
        (const float4*)x, (ushort4*)x2, 8, ROWS * D_MODEL / 4);
    pack3_k<<<2 * D_INNER * D_MODEL / 4 / 256, 256, 0, stream>>>(
        (const float4*)W_in, (ushort4*)Wi2, 8, 2 * D_INNER * D_MODEL / 4);
    // 1) xz = x @ W_in^T  (M=8192, N=4096, K'=3072)
    gemm3k<256><<<dim3(4096 / 256, ROWS / 256), 512, SM1, stream>>>(
        x2, 2 * D_MODEL, Wi2, 3 * D_MODEL, xz, XZ_LD);
    // 2) conv + silu (reads xz, overwrites phase-0 aliases with x_conv)
    conv_silu_k<<<ROWS * 512 / 256, 256, 0, stream>>>(xz, conv_w, conv_b, x_conv);
    // 3) x_proj
    proj_k<<<ROWS / 4, 256, 0, stream>>>(x_conv, W_xproj, A_log, Abar, Bbar, Cm);
    // 4) scan -> y fp32, in place over x_conv
    scan_k<<<dim3(D_INNER / SCH, NB), 256, 0, stream>>>(x_conv, xz, Abar, Bbar, Cm, D_param);
    // 5) pack y -> [hi|lo], W_out -> [hi|hi|lo]  (into now-dead xz region)
    pack2_k<<<ROWS * D_INNER / 4 / 256, 256, 0, stream>>>(
        (const float4*)x_conv, (ushort4*)y2, 9, ROWS * D_INNER / 4);
    pack3_k<<<D_MODEL * D_INNER / 4 / 256, 256, 0, stream>>>(
        (const float4*)W_out, (ushort4*)Wo2, 9, D_MODEL * D_INNER / 4);
    // 6) out = y @ W_out^T  (M=8192, N=1024, K'=6144)
    gemm3k<128><<<dim3(1024 / 256, ROWS / 128), 512, SM2, stream>>>(
        y2, 2 * D_INNER, Wo2, 3 * D_INNER, out, D_MODEL);
}